// Round 9
// baseline (2347.325 us; speedup 1.0000x reference)
//
#include <hip/hip_runtime.h>
#include <cstdint>
#include <cstddef>

#define DEV __device__ __forceinline__

typedef __attribute__((ext_vector_type(4))) float    f32x4;
typedef __attribute__((ext_vector_type(2))) _Float16 f16x2;
typedef __attribute__((ext_vector_type(4))) _Float16 f16x4;
typedef __attribute__((ext_vector_type(8))) _Float16 f16x8;

static constexpr int B_ = 128, T_ = 1024, F_ = 128, H_ = 128, L_ = 7;
static constexpr int M_ = B_ * T_;       // 131072
static constexpr int NCH = 128;          // 8-step chunks per sequence

// ---------- numeric helpers ----------
DEV float fexp2(float x){
#if __has_builtin(__builtin_amdgcn_exp2f)
  return __builtin_amdgcn_exp2f(x);
#else
  return exp2f(x);
#endif
}
DEV float frcp(float x){
#if __has_builtin(__builtin_amdgcn_rcpf)
  return __builtin_amdgcn_rcpf(x);
#else
  return 1.0f/x;
#endif
}
DEV float fsig(float x){ return frcp(1.f + fexp2(-1.44269504f*x)); }
// tanh(x) = 2*sigmoid(2x) - 1 ; saturates correctly via exp2->inf, rcp(inf)=0
DEV float ftanh(float x){ return 2.f*frcp(1.f + fexp2(-2.88539008f*x)) - 1.f; }
DEV void  ntst4(_Float16* p, f16x4 v){ __builtin_nontemporal_store(v, (f16x4*)p); }
DEV f16x8 ntld8(const _Float16* p){ return __builtin_nontemporal_load((const f16x8*)p); }

// ---------- converts ----------
__global__ void k_cvt_x(const float4* __restrict__ x4, f16x4* __restrict__ xo, int n4){
  int i = blockIdx.x*blockDim.x + threadIdx.x;
  int stride = gridDim.x*blockDim.x;
  for (; i < n4; i += stride){
    float4 v = x4[i];
    f16x4 o = {(_Float16)v.x, (_Float16)v.y, (_Float16)v.z, (_Float16)v.w};
    xo[i] = o;
  }
}

// Row order m2 = 32W + 16mt + 4q + r  <->  (gate=r, hrow = 8W + 2q + mt).
// Wc[l][m2][k] f16: k<128 -> Whh[l][r*128+hrow][k], k>=128 -> Wih[l][r*128+hrow][k-128].
// biasc[l][m2] f32 (same m2 order; consumed as float4 at index m2/4).
__global__ void k_cvt_w(const float* __restrict__ Wih, const float* __restrict__ Whh,
                        const float* __restrict__ bih, const float* __restrict__ bhh,
                        _Float16* __restrict__ Wc, float* __restrict__ biasc){
  int idx = blockIdx.x*blockDim.x + threadIdx.x;          // 3584*256 = 917504 exact
  int l    = idx >> 17;            // /(512*256)
  int rem  = idx & 131071;
  int m2   = rem >> 8;
  int k    = rem & 255;
  int W  = m2 >> 5;
  int mt = (m2 >> 4) & 1;
  int q  = (m2 >> 2) & 3;
  int r  = m2 & 3;
  int hrow = 8*W + 2*q + mt;
  int srow = l*512 + r*128 + hrow;
  float v = (k < 128) ? Whh[(size_t)srow*128 + k] : Wih[(size_t)srow*128 + (k-128)];
  Wc[idx] = (_Float16)v;
  if (idx < L_*512){
    int bl = idx >> 9, bm = idx & 511;
    int bW = bm >> 5, bmt = (bm >> 4) & 1, bq = (bm >> 2) & 3, br = bm & 3;
    int bs = bl*512 + br*128 + (8*bW + 2*bq + bmt);
    biasc[idx] = bih[bs] + bhh[bs];
  }
}

// ---------- fused wavefront recurrence: 56 WGs x 1024 threads (16 waves) ----------
// wg = layer*8 + group; 16 batches per WG; wave W owns 32 gate-rows (2 m-tiles)
// = h-rows {8W+2q+mt}. 4 waves/SIMD (VGPR<=128) for phase overlap.
// Per step per wave: 16 MFMA k=32 (8 X-part from global-loaded regs, 8 H-part
// from LDS h broadcast); X-MFMAs issue FIRST (register-ready, fill matrix pipe
// during post-barrier ds_read latency). h double-buffered in LDS; x B-frags
// load 1 row ahead straight global->VGPR (no LDS staging at all).
// Cross-layer: nt h-flush + relaxed agent flags + per-wave vmcnt(0) drain
// every 8 steps (protocol proven R7/R8, absmax 0.0).
__global__ __launch_bounds__(1024) void k_wave(
    const _Float16* __restrict__ xcvt,
    _Float16* __restrict__ buf0, _Float16* __restrict__ buf1,
    const _Float16* __restrict__ Wc, const float4* __restrict__ biasc,
    int* __restrict__ flags){
  const int wg = blockIdx.x;
  const int layer = wg >> 3;
  const int g = wg & 7;
  const int tid = threadIdx.x;
  const int W = tid >> 6;
  const int q = (tid >> 4) & 3;
  const int i = tid & 15;

  const _Float16* src = (layer == 0) ? xcvt : (((layer - 1) & 1) ? buf1 : buf0);
  _Float16* dst = (layer & 1) ? buf1 : buf0;

  __shared__ _Float16 hx[2][16][132];   // h double buffer, bank-clean stride

  // A-frags: wf[mt][kt], A-row m2 = 32W + 16mt + i, k = kt*32 + 8q (kt 0..7; >=4 is X)
  f16x8 wf[2][8];
  {
    const _Float16* wbase = Wc + ((size_t)(layer*512) + 32*W + i)*256 + 8*q;
#pragma unroll
    for (int mt = 0; mt < 2; ++mt)
#pragma unroll
      for (int kt = 0; kt < 8; ++kt)
        wf[mt][kt] = *(const f16x8*)(wbase + (size_t)(16*mt)*256 + 32*kt);
  }
  f32x4 bias0, bias1;
  {
    float4 b0 = biasc[layer*128 + 8*W + q];
    float4 b1 = biasc[layer*128 + 8*W + 4 + q];
    bias0 = f32x4{b0.x, b0.y, b0.z, b0.w};
    bias1 = f32x4{b1.x, b1.y, b1.z, b1.w};
  }
  float c0 = 0.f, c1 = 0.f;

  // x B-frag source: batch i, k-offset 8q (per-lane global address)
  const _Float16* xbase = src + ((size_t)(g*16 + i))*T_*H_ + 8*q;
  // flush roles (tid < 512): batch bb, 4-elem chunk cc
  const int bb = tid >> 5;
  const int cc = tid & 31;
  _Float16* hdst = dst + ((size_t)(g*16 + (bb & 15)))*T_*H_ + cc*4;
  int* fIn  = flags + ((layer > 0 ? layer - 1 : 0)*8 + g)*NCH;
  int* fOut = flags + (layer*8 + g)*NCH;

  auto poll = [&](int* p){
    if (tid == 0){
      while (__hip_atomic_load(p, __ATOMIC_RELAXED, __HIP_MEMORY_SCOPE_AGENT) == 0)
        __builtin_amdgcn_s_sleep(2);
    }
    __syncthreads();
  };

  // ---- prologue: gate chunk 0, zero h state, load x row 0 frags ----
  if (layer > 0) poll(fIn + 0);
  if (tid < 512){
    f16x4 z4 = {(_Float16)0.f, (_Float16)0.f, (_Float16)0.f, (_Float16)0.f};
    *(f16x4*)&hx[0][bb][cc*4] = z4;
  }
  f16x8 bx0 = *(const f16x8*)(xbase +  0);
  f16x8 bx1 = *(const f16x8*)(xbase + 32);
  f16x8 bx2 = *(const f16x8*)(xbase + 64);
  f16x8 bx3 = *(const f16x8*)(xbase + 96);
  __syncthreads();

#define MF(Wf, Bf, Acc) Acc = __builtin_amdgcn_mfma_f32_16x16x32_f16(Wf, Bf, Acc, 0, 0, 0)

#define BODY(CUR, TT)                                                            \
  {                                                                              \
    f16x4 freg = {};                                                             \
    if ((TT) > 0 && tid < 512) freg = *(const f16x4*)&hx[CUR][bb][cc*4];         \
    f32x4 a0 = bias0, a1 = bias1;                                                \
    /* X part first: registers ready, warms matrix pipe */                       \
    MF(wf[0][4], bx0, a0); MF(wf[1][4], bx0, a1);                                \
    MF(wf[0][5], bx1, a0); MF(wf[1][5], bx1, a1);                                \
    MF(wf[0][6], bx2, a0); MF(wf[1][6], bx2, a1);                                \
    MF(wf[0][7], bx3, a0); MF(wf[1][7], bx3, a1);                                \
    /* h B-frags from LDS */                                                     \
    f16x8 bf0 = *(const f16x8*)&hx[CUR][i][ 0 + 8*q];                            \
    f16x8 bf1 = *(const f16x8*)&hx[CUR][i][32 + 8*q];                            \
    f16x8 bf2 = *(const f16x8*)&hx[CUR][i][64 + 8*q];                            \
    f16x8 bf3 = *(const f16x8*)&hx[CUR][i][96 + 8*q];                            \
    /* issue next-row x loads (1 ahead; gated by poll at chunk crossings) */     \
    { int rp = (TT) + 1; if (rp > T_ - 1) rp = T_ - 1;                           \
      const _Float16* xr = xbase + (size_t)rp*H_;                                \
      bx0 = *(const f16x8*)(xr +  0);                                            \
      bx1 = *(const f16x8*)(xr + 32);                                            \
      bx2 = *(const f16x8*)(xr + 64);                                            \
      bx3 = *(const f16x8*)(xr + 96); }                                          \
    /* H part */                                                                 \
    MF(wf[0][0], bf0, a0); MF(wf[1][0], bf0, a1);                                \
    MF(wf[0][1], bf1, a0); MF(wf[1][1], bf1, a1);                                \
    MF(wf[0][2], bf2, a0); MF(wf[1][2], bf2, a1);                                \
    MF(wf[0][3], bf3, a0); MF(wf[1][3], bf3, a1);                                \
    if ((TT) > 0 && tid < 512) ntst4(hdst + (size_t)((TT) - 1)*H_, freg);        \
    /* gates: rows 8W+2q (a0) and 8W+2q+1 (a1), batch i */                       \
    float h0, h1;                                                                \
    { float si = fsig(a0[0]), sf = fsig(a0[1]);                                  \
      float gt = ftanh(a0[2]), so = fsig(a0[3]);                                 \
      c0 = sf*c0 + si*gt; h0 = so*ftanh(c0); }                                   \
    { float si = fsig(a1[0]), sf = fsig(a1[1]);                                  \
      float gt = ftanh(a1[2]), so = fsig(a1[3]);                                 \
      c1 = sf*c1 + si*gt; h1 = so*ftanh(c1); }                                   \
    f16x2 hv = {(_Float16)h0, (_Float16)h1};                                     \
    *(f16x2*)&hx[(CUR) ^ 1][i][8*W + 2*q] = hv;                                  \
    asm volatile("s_waitcnt lgkmcnt(0)\n\ts_barrier" ::: "memory");              \
  }

  for (int t = 0; t < T_; t += 2){
    BODY(0, t)
    // publish chunk (t/8 - 1): rows <= t-1 flushed; drain to MALL then flag
    if (layer < 6 && t > 0 && (t & 7) == 0){
      asm volatile("s_waitcnt vmcnt(0)" ::: "memory");
      __syncthreads();
      if (tid == 0)
        __hip_atomic_store(fOut + ((t >> 3) - 1), 1, __ATOMIC_RELAXED, __HIP_MEMORY_SCOPE_AGENT);
    }
    // odd body loads row t+2; gate its chunk
    if (layer > 0 && ((t + 2) & 7) == 0 && (t + 2) < T_) poll(fIn + ((t + 2) >> 3));
    BODY(1, t + 1)
  }
#undef BODY
#undef MF

  // final flush: h(1023) lives in hx[0]
  if (tid < 512){
    f16x4 freg = *(const f16x4*)&hx[0][bb][cc*4];
    ntst4(hdst + (size_t)(T_ - 1)*H_, freg);
  }
  if (layer < 6){
    asm volatile("s_waitcnt vmcnt(0)" ::: "memory");
    __syncthreads();
    if (tid == 0)
      __hip_atomic_store(fOut + (NCH - 1), 1, __ATOMIC_RELAXED, __HIP_MEMORY_SCOPE_AGENT);
  }
}

// ---------- attention (only head A-1 matters) + final linear + sigmoid ----------
// nt loads: the h buffer was written with nt stores (MALL-coherent, L2-bypassed);
// reading nt avoids any stale-L2 window.
__global__ __launch_bounds__(256) void k_attn(const _Float16* __restrict__ out,
                                              const float* __restrict__ Wa, const float* __restrict__ ba,
                                              const float* __restrict__ Wf, const float* __restrict__ bfv,
                                              float* __restrict__ y){
  int b = blockIdx.x, tid = threadIdx.x;
  __shared__ float was[H_];
  __shared__ float p[T_];
  __shared__ float red[64];
  __shared__ float app[256];
  if (tid < H_) was[tid] = Wa[127*H_ + tid];
  __syncthreads();
  float bav = ba[127];
  for (int t = tid; t < T_; t += 256){
    const _Float16* row = out + (size_t)(b*T_ + t)*H_;
    float acc = 0.f;
#pragma unroll
    for (int k = 0; k < H_; k += 8){
      f16x8 u = ntld8(row + k);
      acc += (float)u[0]*was[k+0] + (float)u[1]*was[k+1]
           + (float)u[2]*was[k+2] + (float)u[3]*was[k+3]
           + (float)u[4]*was[k+4] + (float)u[5]*was[k+5]
           + (float)u[6]*was[k+6] + (float)u[7]*was[k+7];
    }
    p[t] = ftanh(acc + bav);
  }
  __syncthreads();
  float m = -1e30f;
  for (int t = tid; t < T_; t += 256) m = fmaxf(m, p[t]);
  for (int off = 32; off; off >>= 1) m = fmaxf(m, __shfl_xor(m, off));
  if ((tid & 63) == 0) red[tid >> 6] = m;
  __syncthreads();
  if (tid == 0) red[8] = fmaxf(fmaxf(red[0], red[1]), fmaxf(red[2], red[3]));
  __syncthreads();
  float smax = red[8];
  float lsum = 0.f;
  for (int t = tid; t < T_; t += 256){
    float e = fexp2(1.44269504f*(p[t] - smax));
    p[t] = e; lsum += e;
  }
  for (int off = 32; off; off >>= 1) lsum += __shfl_xor(lsum, off);
  if ((tid & 63) == 0) red[16 + (tid >> 6)] = lsum;
  __syncthreads();
  float rden = frcp(red[16] + red[17] + red[18] + red[19]);
  int h = tid & (H_ - 1);
  int half = tid >> 7;
  float acc = 0.f;
  for (int t = half*512; t < half*512 + 512; ++t)
    acc += p[t] * (float)__builtin_nontemporal_load(out + (size_t)(b*T_ + t)*H_ + h);
  app[tid] = acc;
  __syncthreads();
  if (tid < H_){
    float applied = (app[tid] + app[tid + H_]) * rden;
    float v = applied * Wf[tid];
    for (int off = 32; off; off >>= 1) v += __shfl_xor(v, off);
    if (tid == 0)  red[32] = v;
    if (tid == 64) red[33] = v;
  }
  __syncthreads();
  if (tid == 0) y[b] = fsig(red[32] + red[33] + bfv[0]);
}

// ---------- launch ----------
extern "C" void kernel_launch(void* const* d_in, const int* in_sizes, int n_in,
                              void* d_out, int out_size, void* d_ws, size_t ws_size,
                              hipStream_t stream){
  const float* x   = (const float*)d_in[0];
  const float* Wih = (const float*)d_in[1];
  const float* Whh = (const float*)d_in[2];
  const float* bih = (const float*)d_in[3];
  const float* bhh = (const float*)d_in[4];
  const float* Wa  = (const float*)d_in[5];
  const float* ba  = (const float*)d_in[6];
  const float* Wf  = (const float*)d_in[7];
  const float* bfv = (const float*)d_in[8];
  float* y = (float*)d_out;

  char* ws = (char*)d_ws;
  size_t off = 0;
  auto alloc = [&](size_t bytes) -> void* {
    void* p = ws + off; off += (bytes + 255) & ~(size_t)255; return p;
  };
  _Float16* xcvt  = (_Float16*)alloc((size_t)M_*H_*2);       // 33.5 MB
  _Float16* buf0  = (_Float16*)alloc((size_t)M_*H_*2);       // 33.5 MB
  _Float16* buf1  = (_Float16*)alloc((size_t)M_*H_*2);       // 33.5 MB
  _Float16* Wc    = (_Float16*)alloc((size_t)L_*512*256*2);  // 1.8 MB
  float*    biasc = (float*)   alloc((size_t)L_*512*4);      // 14 KB
  int*      flags = (int*)     alloc((size_t)L_*8*NCH*4);    // 28 KB

  hipMemsetAsync(flags, 0, (size_t)L_*8*NCH*4, stream);
  k_cvt_x<<<2048, 256, 0, stream>>>((const float4*)x, (f16x4*)xcvt, M_*F_/4);
  k_cvt_w<<<3584, 256, 0, stream>>>(Wih, Whh, bih, bhh, Wc, biasc);
  k_wave<<<56, 1024, 0, stream>>>(xcvt, buf0, buf1, Wc, (const float4*)biasc, flags);
  k_attn<<<128, 256, 0, stream>>>(buf0, Wa, ba, Wf, bfv, y);
}